// Round 16
// baseline (1562.602 us; speedup 1.0000x reference)
//
#include <hip/hip_runtime.h>
#include <hip/hip_bf16.h>

#define EMBD 300
#define GG   4096
#define NLAY 5
#define KP1  320   // padded K for EMB=300 inputs (h / aggB row stride)
#define KP2  640   // W2 weight-plane K stride
#define KT2  608   // t-buffer row stride (19 x 32)
#define NP1  640   // padded out-cols for 600
#define NP2  384   // padded out-cols for 300 (3 x 128)
#define WPER (NP1*KP1 + NP2*KP2)   // 450560 elems per MLP weight set

typedef unsigned short ushort_t;
typedef short short8 __attribute__((ext_vector_type(8)));
typedef short short4v __attribute__((ext_vector_type(4)));
typedef float f32x4 __attribute__((ext_vector_type(4)));

static inline int cdiv(int a, int b) { return (a + b - 1) / b; }

// ---------------- helpers ----------------

__device__ inline void dma16(const ushort_t* g, ushort_t* l) {
    __builtin_amdgcn_global_load_lds(
        (const __attribute__((address_space(1))) unsigned int*)g,
        (__attribute__((address_space(3))) unsigned int*)l, 16, 0, 0);
}

__device__ inline ushort_t bf16_of(float v) {
    union { __hip_bfloat16 b; ushort_t u; } c;
    c.b = __float2bfloat16(v);
    return c.u;
}

__device__ inline float bf2f(ushort_t u) {
    union { unsigned int i; float f; } c;
    c.i = ((unsigned int)u) << 16;
    return c.f;
}

// ---------------- init kernels ----------------

// atom encode + vn0 broadcast -> h bf16 [N][KP1]
__global__ void atom_encode_bf(const int* __restrict__ x, const float* __restrict__ aemb,
                               const float* __restrict__ vn_emb,
                               ushort_t* __restrict__ h, int N) {
    int i = blockIdx.x * blockDim.x + threadIdx.x;
    int total = N * 75;
    if (i >= total) return;
    int n = i / 75, d4 = i - n * 75;
    const int* xr = x + n * 9;
    float4 s = ((const float4*)vn_emb)[d4];   // + vn_0
    const float4* a4 = (const float4*)aemb;
#pragma unroll
    for (int f = 0; f < 9; ++f) {
        float4 v = a4[(size_t)((f << 7) + xr[f]) * 75 + d4];
        s.x += v.x; s.y += v.y; s.z += v.z; s.w += v.w;
    }
    short4v o;
    o[0] = (short)bf16_of(s.x); o[1] = (short)bf16_of(s.y);
    o[2] = (short)bf16_of(s.z); o[3] = (short)bf16_of(s.w);
    *(short4v*)(h + (size_t)n * KP1 + d4 * 4) = o;
}

__global__ void init_vn4(const float* __restrict__ vn_emb, float* __restrict__ vn) {
    int i = blockIdx.x * blockDim.x + threadIdx.x;
    if (i >= GG * 75) return;
    ((float4*)vn)[i] = ((const float4*)vn_emb)[i % 75];
}

__global__ void find_starts(const int* __restrict__ batch, int* __restrict__ starts, int N) {
    int g = blockIdx.x * blockDim.x + threadIdx.x;
    if (g > GG) return;
    int lo = 0, hi = N;
    while (lo < hi) {
        int mid = (lo + hi) >> 1;
        if (batch[mid] < g) lo = mid + 1; else hi = mid;
    }
    starts[g] = lo;
}

__global__ void bond_combo(const float* __restrict__ bemb, float* __restrict__ ebsum) {
    int i = blockIdx.x * blockDim.x + threadIdx.x;
    if (i >= 512 * EMBD) return;
    int c = i / EMBD, d = i - c * EMBD;
    int a0 = c >> 6, a1 = (c >> 3) & 7, a2 = c & 7;
    ebsum[i] = bemb[a0 * EMBD + d] + bemb[(8 + a1) * EMBD + d] + bemb[(16 + a2) * EMBD + d];
}

__global__ void conv_all(const float* __restrict__ gW1, const float* __restrict__ gW2,
                         const float* __restrict__ vW1, const float* __restrict__ vW2,
                         ushort_t* __restrict__ wh) {
    int i = blockIdx.x * blockDim.x + threadIdx.x;
    int total = WPER * 9;
    if (i >= total) return;
    int mlp = i / WPER, r = i - mlp * WPER;
    const float *W1, *W2;
    if (mlp < NLAY) {
        W1 = gW1 + (size_t)mlp * EMBD * 2 * EMBD;
        W2 = gW2 + (size_t)mlp * 2 * EMBD * EMBD;
    } else {
        int l = mlp - NLAY;
        W1 = vW1 + (size_t)l * EMBD * 2 * EMBD;
        W2 = vW2 + (size_t)l * 2 * EMBD * EMBD;
    }
    float v;
    if (r < NP1 * KP1) {
        int n = r / KP1, k = r - n * KP1;
        v = (n < 2 * EMBD && k < EMBD) ? W1[(size_t)k * (2 * EMBD) + n] : 0.f;
    } else {
        int r2 = r - NP1 * KP1;
        int n = r2 / KP2, k = r2 - n * KP2;
        v = (n < EMBD && k < 2 * EMBD) ? W2[(size_t)k * EMBD + n] : 0.f;
    }
    wh[i] = bf16_of(v);
}

// ---------------- edge bucket sort ----------------

__global__ void ecount(const int* __restrict__ ei, int* __restrict__ cnt, int E) {
    int e = blockIdx.x * blockDim.x + threadIdx.x;
    if (e >= E) return;
    atomicAdd(&cnt[ei[E + e]], 1);
}

__global__ void scan_part(const int* __restrict__ cnt, int* __restrict__ bsum, int N) {
    __shared__ int sh[256];
    int b = blockIdx.x, t = threadIdx.x;
    int base = b * 1024;
    int s = 0;
    for (int j = t; j < 1024; j += 256) {
        int idx = base + j;
        if (idx < N) s += cnt[idx];
    }
    sh[t] = s;
    __syncthreads();
    for (int d = 128; d > 0; d >>= 1) {
        if (t < d) sh[t] += sh[t + d];
        __syncthreads();
    }
    if (t == 0) bsum[b] = sh[0];
}

__global__ void scan_top(int* __restrict__ bsum, int nb) {
    __shared__ int sh[1024];
    int t = threadIdx.x;
    int v = (t < nb) ? bsum[t] : 0;
    sh[t] = v;
    __syncthreads();
    for (int d = 1; d < 1024; d <<= 1) {
        int u = (t >= d) ? sh[t - d] : 0;
        __syncthreads();
        sh[t] += u;
        __syncthreads();
    }
    if (t < nb) bsum[t] = sh[t] - v;  // exclusive
}

__global__ void scan_final(int* __restrict__ cnt, const int* __restrict__ bsum,
                           int* __restrict__ estart, int* __restrict__ cursor, int N, int E) {
    __shared__ int sh[256];
    int b = blockIdx.x, t = threadIdx.x;
    int base = b * 1024 + t * 4;
    int c[4];
    int s = 0;
#pragma unroll
    for (int j = 0; j < 4; ++j) {
        int idx = base + j;
        c[j] = (idx < N) ? cnt[idx] : 0;
        s += c[j];
    }
    sh[t] = s;
    __syncthreads();
    for (int d = 1; d < 256; d <<= 1) {
        int u = (t >= d) ? sh[t - d] : 0;
        __syncthreads();
        sh[t] += u;
        __syncthreads();
    }
    int run = sh[t] - s + bsum[b];
#pragma unroll
    for (int j = 0; j < 4; ++j) {
        int idx = base + j;
        if (idx < N) { estart[idx] = run; cursor[idx] = run; run += c[j]; }
    }
    if (b == 0 && t == 0) estart[N] = E;
}

__global__ void escatter(const int* __restrict__ ei, const int* __restrict__ ea,
                         int* __restrict__ cursor, int* __restrict__ epack, int E) {
    int e = blockIdx.x * blockDim.x + threadIdx.x;
    if (e >= E) return;
    int c = ei[E + e];
    int p = atomicAdd(&cursor[c], 1);
    epack[p] = (ei[e] << 9) | (ea[3 * e] << 6) | (ea[3 * e + 1] << 3) | ea[3 * e + 2];
}

// ---------------- per-layer elementwise (h bf16 [N][KP1], ALWAYS includes vn) ----------------

// read-only pool: vnaB[g] = bf16(segment_sum(h) + vn[g]); vectorized 4 graphs/block
__global__ void pool_only(const ushort_t* __restrict__ h, const float* __restrict__ vn,
                          const int* __restrict__ starts, ushort_t* __restrict__ vnaB) {
    int g = blockIdx.x * 4 + threadIdx.x / 80;
    int slot = threadIdx.x % 80;
    if (g >= GG || slot >= 75) return;
    float4 vng = ((const float4*)vn)[(size_t)g * 75 + slot];
    int s0 = starts[g], s1 = starts[g + 1];
    float4 s = make_float4(0.f, 0.f, 0.f, 0.f);
    for (int n = s0; n < s1; ++n) {
        short4v hv = *(const short4v*)(h + (size_t)n * KP1 + slot * 4);
        s.x += bf2f((ushort_t)hv[0]);
        s.y += bf2f((ushort_t)hv[1]);
        s.z += bf2f((ushort_t)hv[2]);
        s.w += bf2f((ushort_t)hv[3]);
    }
    short4v o;
    o[0] = (short)bf16_of(s.x + vng.x); o[1] = (short)bf16_of(s.y + vng.y);
    o[2] = (short)bf16_of(s.z + vng.z); o[3] = (short)bf16_of(s.w + vng.w);
    *(short4v*)(vnaB + (size_t)g * KP1 + slot * 4) = o;
}

__global__ void pool_mean(const ushort_t* __restrict__ h, const int* __restrict__ starts,
                          float* __restrict__ out) {
    int g = blockIdx.x * 4 + threadIdx.x / 80;
    int slot = threadIdx.x % 80;
    if (g >= GG || slot >= 75) return;
    int s0 = starts[g], s1 = starts[g + 1];
    float4 s = make_float4(0.f, 0.f, 0.f, 0.f);
    for (int n = s0; n < s1; ++n) {
        short4v hv = *(const short4v*)(h + (size_t)n * KP1 + slot * 4);
        s.x += bf2f((ushort_t)hv[0]);
        s.y += bf2f((ushort_t)hv[1]);
        s.z += bf2f((ushort_t)hv[2]);
        s.w += bf2f((ushort_t)hv[3]);
    }
    float inv = 1.0f / fmaxf((float)(s1 - s0), 1.0f);
    float4 o = make_float4(s.x * inv, s.y * inv, s.z * inv, s.w * inv);
    ((float4*)out)[(size_t)g * 75 + slot] = o;
}

// ---------------- fused aggregate (2-edge unroll, packed epack) ----------------
#define NPB 4   // nodes per block; blockDim = NPB*80 = 320

__global__ void aggregate(const ushort_t* __restrict__ h, const float* __restrict__ ebsum,
                          const int* __restrict__ estart, const int* __restrict__ epack,
                          const float* __restrict__ epsp,
                          ushort_t* __restrict__ aggB, int N) {
    int n = blockIdx.x * NPB + threadIdx.x / 80;
    int slot = threadIdx.x % 80;
    if (n >= N) return;
    float4 acc = make_float4(0.f, 0.f, 0.f, 0.f);
    if (slot < 75) {
        const float4* b4 = (const float4*)ebsum;
        float ce = 1.0f + *epsp;
        short4v hv = *(const short4v*)(h + (size_t)n * KP1 + slot * 4);
        acc.x = ce * bf2f((ushort_t)hv[0]);
        acc.y = ce * bf2f((ushort_t)hv[1]);
        acc.z = ce * bf2f((ushort_t)hv[2]);
        acc.w = ce * bf2f((ushort_t)hv[3]);
        int p0 = estart[n], p1 = estart[n + 1];
        int p = p0;
        for (; p + 2 <= p1; p += 2) {
            int e0 = epack[p], e1 = epack[p + 1];
            short4v xv0 = *(const short4v*)(h + (size_t)(e0 >> 9) * KP1 + slot * 4);
            short4v xv1 = *(const short4v*)(h + (size_t)(e1 >> 9) * KP1 + slot * 4);
            float4 ev0 = b4[(size_t)(e0 & 511) * 75 + slot];
            float4 ev1 = b4[(size_t)(e1 & 511) * 75 + slot];
            acc.x += fmaxf(bf2f((ushort_t)xv0[0]) + ev0.x, 0.f) + fmaxf(bf2f((ushort_t)xv1[0]) + ev1.x, 0.f);
            acc.y += fmaxf(bf2f((ushort_t)xv0[1]) + ev0.y, 0.f) + fmaxf(bf2f((ushort_t)xv1[1]) + ev1.y, 0.f);
            acc.z += fmaxf(bf2f((ushort_t)xv0[2]) + ev0.z, 0.f) + fmaxf(bf2f((ushort_t)xv1[2]) + ev1.z, 0.f);
            acc.w += fmaxf(bf2f((ushort_t)xv0[3]) + ev0.w, 0.f) + fmaxf(bf2f((ushort_t)xv1[3]) + ev1.w, 0.f);
        }
        if (p < p1) {
            int e0 = epack[p];
            short4v xv0 = *(const short4v*)(h + (size_t)(e0 >> 9) * KP1 + slot * 4);
            float4 ev0 = b4[(size_t)(e0 & 511) * 75 + slot];
            acc.x += fmaxf(bf2f((ushort_t)xv0[0]) + ev0.x, 0.f);
            acc.y += fmaxf(bf2f((ushort_t)xv0[1]) + ev0.y, 0.f);
            acc.z += fmaxf(bf2f((ushort_t)xv0[2]) + ev0.z, 0.f);
            acc.w += fmaxf(bf2f((ushort_t)xv0[3]) + ev0.w, 0.f);
        }
    }
    short4v bv4;
    bv4[0] = (short)bf16_of(acc.x);
    bv4[1] = (short)bf16_of(acc.y);
    bv4[2] = (short)bf16_of(acc.z);
    bv4[3] = (short)bf16_of(acc.w);
    *(short4v*)(aggB + (size_t)n * KP1 + slot * 4) = bv4;
}

// ---------------- MFMA GEMM: bf16 A,B; 128x128 tile; 2-stage LDS; XCD swizzle ----------------
// bf16 out path: LDS-staged full-line stores; optional writer-side vn-add (contiguous loads).
#define BMg 128
#define BNg 128
#define STG (BMg * 32)

__global__ __launch_bounds__(256) void gemm_as(
    const ushort_t* __restrict__ A, int KPA,
    const ushort_t* __restrict__ B, int KPB,
    const float* __restrict__ bias, const float* __restrict__ gg,
    const float* __restrict__ bb, const float* __restrict__ bm,
    const float* __restrict__ bv,
    int Mc, int NnReal, int relu, int nb, int mb,
    const float* __restrict__ vnadd, const int* __restrict__ batchp,
    float* __restrict__ outF, int ldF,
    ushort_t* __restrict__ outB, int ldP)
{
    __shared__ ushort_t smem[4 * STG];   // 32 KB: [A0|A1|B0|B1] during K-loop; C-tile after

    int id = blockIdx.x;
    int hi = id / (8 * nb);
    int rem = id - hi * 8 * nb;
    int xcd = rem & 7;
    int nblk = rem >> 3;
    int mblk = hi * 8 + xcd;
    if (mblk >= mb) return;

    const int tid = threadIdx.x;
    const int lane = tid & 63;
    const int w = tid >> 6;
    const int m0 = mblk * BMg;
    const int n0 = nblk * BNg;
    const int wm = (w & 1) * 64;
    const int wn = (w >> 1) * 64;

    const ushort_t* gA[2];
    const ushort_t* gB[2];
    int lbase[2];
#pragma unroll
    for (int i = 0; i < 2; ++i) {
        int s = tid + 256 * i;
        int m = s >> 2, qp = s & 3;
        int q = (qp - (m >> 1)) & 3;
        int msrc = (m0 + m < Mc) ? (m0 + m) : (Mc - 1);
        gA[i] = A + (size_t)msrc * KPA + 8 * q;
        gB[i] = B + (size_t)(n0 + m) * KPB + 8 * q;   // B rows fully padded
        lbase[i] = (w * 64 + 256 * i) * 8;
    }

    f32x4 acc[4][4];
#pragma unroll
    for (int a = 0; a < 4; ++a)
#pragma unroll
        for (int b = 0; b < 4; ++b) acc[a][b] = (f32x4)(0.f);

    const int q = lane >> 4;
    const int c16 = lane & 15;
    const int kt = KPA >> 5;

#pragma unroll
    for (int i = 0; i < 2; ++i) {
        dma16(gA[i], smem + lbase[i]);           gA[i] += 32;
        dma16(gB[i], smem + 2 * STG + lbase[i]); gB[i] += 32;
    }
    __syncthreads();

    for (int t = 0; t < kt; ++t) {
        int cur = t & 1, nxt = cur ^ 1;
        if (t + 1 < kt) {
#pragma unroll
            for (int i = 0; i < 2; ++i) {
                dma16(gA[i], smem + nxt * STG + lbase[i]);       gA[i] += 32;
                dma16(gB[i], smem + (2 + nxt) * STG + lbase[i]); gB[i] += 32;
            }
        }
        const ushort_t* sAc = smem + cur * STG;
        const ushort_t* sBc = smem + (2 + cur) * STG;
        short8 av[4], bhv[4];
#pragma unroll
        for (int tt = 0; tt < 4; ++tt) {
            int m = wm + tt * 16 + c16;
            int q2 = (q + (m >> 1)) & 3;
            av[tt] = *(const short8*)(sAc + m * 32 + q2 * 8);
        }
#pragma unroll
        for (int uu = 0; uu < 4; ++uu) {
            int n = wn + uu * 16 + c16;
            int q2 = (q + (n >> 1)) & 3;
            bhv[uu] = *(const short8*)(sBc + n * 32 + q2 * 8);
        }
#pragma unroll
        for (int tt = 0; tt < 4; ++tt)
#pragma unroll
            for (int uu = 0; uu < 4; ++uu)
                acc[tt][uu] = __builtin_amdgcn_mfma_f32_16x16x32_bf16(av[tt], bhv[uu], acc[tt][uu], 0, 0, 0);
        __syncthreads();
    }

    // ---- epilogue: bn (+relu); C/D layout col=lane&15, row=q*4+r ----
    float sc[4], sh[4];
#pragma unroll
    for (int uu = 0; uu < 4; ++uu) {
        int gn = n0 + wn + uu * 16 + c16;
        if (gn < NnReal) {
            float s = gg[gn] * rsqrtf(bv[gn] + 1e-5f);
            sc[uu] = s;
            sh[uu] = bb[gn] + (bias[gn] - bm[gn]) * sc[uu];
        } else { sc[uu] = 0.f; sh[uu] = 0.f; }
    }

    if (outB) {
        // stage C tile in LDS (q*16-col rotation), then full-line stores; optional vn-add
        const int rot = q * 16;
#pragma unroll
        for (int uu = 0; uu < 4; ++uu) {
#pragma unroll
            for (int tt = 0; tt < 4; ++tt) {
                int row = wm + tt * 16 + q * 4;
#pragma unroll
                for (int r = 0; r < 4; ++r) {
                    float y = acc[tt][uu][r] * sc[uu] + sh[uu];
                    if (relu) y = fmaxf(y, 0.f);
                    int col_s = (wn + uu * 16 + c16 + rot) & 127;
                    smem[(row + r) * 128 + col_s] = bf16_of(y);
                }
            }
        }
        __syncthreads();
#pragma unroll
        for (int j = 0; j < 8; ++j) {
            int row = j * 16 + q * 4 + w;          // (row>>2)&3 == q -> matches writer rotation
            int gm = m0 + row;
            int gcl = c16 * 8;
            if (gm < Mc && n0 + gcl + 8 <= ldP) {
                short8 v = *(const short8*)(smem + row * 128 + ((gcl + rot) & 127));
                if (vnadd) {
                    const float* vrow = vnadd + (size_t)batchp[gm] * EMBD;
                    int colb = n0 + gcl;
                    if (colb + 8 <= EMBD) {
                        float4 a = *(const float4*)(vrow + colb);
                        float4 b = *(const float4*)(vrow + colb + 4);
                        v[0] = (short)bf16_of(bf2f((ushort_t)v[0]) + a.x);
                        v[1] = (short)bf16_of(bf2f((ushort_t)v[1]) + a.y);
                        v[2] = (short)bf16_of(bf2f((ushort_t)v[2]) + a.z);
                        v[3] = (short)bf16_of(bf2f((ushort_t)v[3]) + a.w);
                        v[4] = (short)bf16_of(bf2f((ushort_t)v[4]) + b.x);
                        v[5] = (short)bf16_of(bf2f((ushort_t)v[5]) + b.y);
                        v[6] = (short)bf16_of(bf2f((ushort_t)v[6]) + b.z);
                        v[7] = (short)bf16_of(bf2f((ushort_t)v[7]) + b.w);
                    } else if (colb < EMBD) {
#pragma unroll
                        for (int k = 0; k < 8; ++k)
                            if (colb + k < EMBD)
                                v[k] = (short)bf16_of(bf2f((ushort_t)v[k]) + vrow[colb + k]);
                    }
                }
                *(short8*)(outB + (size_t)gm * ldP + n0 + gcl) = v;
            }
        }
    } else {
#pragma unroll
        for (int uu = 0; uu < 4; ++uu) {
            int gn = n0 + wn + uu * 16 + c16;
#pragma unroll
            for (int tt = 0; tt < 4; ++tt) {
                int rbase = m0 + wm + tt * 16 + q * 4;
#pragma unroll
                for (int r = 0; r < 4; ++r) {
                    int gm = rbase + r;
                    if (gm >= Mc) continue;
                    float y = acc[tt][uu][r] * sc[uu] + sh[uu];
                    if (relu) y = fmaxf(y, 0.f);
                    if (gn < NnReal) outF[(size_t)gm * ldF + gn] = y;
                }
            }
        }
    }
}

// ---------------- host-side MLP ----------------

struct MlpP {
    const float *b1, *g1, *be1, *m1, *v1;
    const float *b2, *g2, *be2, *m2, *v2;
};

static void run_mlp(hipStream_t stream, const ushort_t* inB, int M,
                    const ushort_t* wh, int mlp,
                    ushort_t* tB, int CH,
                    const MlpP& W, ushort_t* outB, int relu2,
                    const float* vnadd, const int* batch) {
    const ushort_t* w1 = wh + (size_t)mlp * WPER;
    const ushort_t* w2 = w1 + NP1 * KP1;
    for (int c0 = 0; c0 < M; c0 += CH) {
        int Mc = (M - c0 < CH) ? (M - c0) : CH;
        int mb = cdiv(Mc, BMg);
        int mbp = cdiv(mb, 8) * 8;
        {
            int nb = NP1 / BNg;   // 5
            gemm_as<<<nb * mbp, 256, 0, stream>>>(
                inB + (size_t)c0 * KP1, KP1, w1, KP1,
                W.b1, W.g1, W.be1, W.m1, W.v1,
                Mc, 2 * EMBD, 1, nb, mb,
                nullptr, nullptr,
                nullptr, 0, tB, KT2);
        }
        {
            int nb = NP2 / BNg;   // 3
            gemm_as<<<nb * mbp, 256, 0, stream>>>(
                tB, KT2, w2, KP2,
                W.b2, W.g2, W.be2, W.m2, W.v2,
                Mc, EMBD, relu2, nb, mb,
                vnadd, vnadd ? (batch + c0) : nullptr,
                nullptr, 0, outB + (size_t)c0 * KP1, KP1);
        }
    }
}

// ---------------- entry ----------------

extern "C" void kernel_launch(void* const* d_in, const int* in_sizes, int n_in,
                              void* d_out, int out_size, void* d_ws, size_t ws_size,
                              hipStream_t stream) {
    const int*   x        = (const int*)d_in[0];
    const int*   ei       = (const int*)d_in[1];
    const int*   ea       = (const int*)d_in[2];
    const int*   batch    = (const int*)d_in[3];
    const float* atom_emb = (const float*)d_in[4];
    const float* bond_emb = (const float*)d_in[5];
    const float* vn_emb   = (const float*)d_in[6];
    const float* gin_eps  = (const float*)d_in[7];
    const float* gin_W1   = (const float*)d_in[8];
    const float* gin_b1   = (const float*)d_in[9];
    const float* gin_bn1g = (const float*)d_in[10];
    const float* gin_bn1b = (const float*)d_in[11];
    const float* gin_bn1m = (const float*)d_in[12];
    const float* gin_bn1v = (const float*)d_in[13];
    const float* gin_W2   = (const float*)d_in[14];
    const float* gin_b2   = (const float*)d_in[15];
    const float* bn_g     = (const float*)d_in[16];
    const float* bn_b     = (const float*)d_in[17];
    const float* bn_m     = (const float*)d_in[18];
    const float* bn_v     = (const float*)d_in[19];
    const float* vn_W1    = (const float*)d_in[20];
    const float* vn_b1    = (const float*)d_in[21];
    const float* vn_bn1g  = (const float*)d_in[22];
    const float* vn_bn1b  = (const float*)d_in[23];
    const float* vn_bn1m  = (const float*)d_in[24];
    const float* vn_bn1v  = (const float*)d_in[25];
    const float* vn_W2    = (const float*)d_in[26];
    const float* vn_b2    = (const float*)d_in[27];
    const float* vn_bn2g  = (const float*)d_in[28];
    const float* vn_bn2b  = (const float*)d_in[29];
    const float* vn_bn2m  = (const float*)d_in[30];
    const float* vn_bn2v  = (const float*)d_in[31];

    const int N = in_sizes[3];
    const int E = in_sizes[1] / 2;
    const int NB = cdiv(N, 1024);

    // ---- workspace layout (bytes); fixed ~146 MB of the ~256 MiB budget ----
    char* base = (char*)d_ws;
    size_t off = 0;
    ushort_t* hbuf = (ushort_t*)(base + off); off += (size_t)N * KP1 * 2;    // 64 MB
    ushort_t* aggB = (ushort_t*)(base + off); off += (size_t)N * KP1 * 2;    // 64 MB
    float* vnbuf   = (float*)(base + off);    off += (size_t)GG * EMBD * 4;  // 4.9 MB
    int*   starts  = (int*)(base + off);      off += 4104 * 4;
    int*   cnt     = (int*)(base + off);      off += (size_t)N * 4;          // doubles as cursor
    int*   estart  = (int*)(base + off);      off += ((size_t)N + 8) * 4;
    int*   bsum    = (int*)(base + off);      off += 1032 * 4;
    int*   epack   = (int*)(base + off);      off += (size_t)E * 4;          // 1 MB packed
    float* ebsum   = (float*)(base + off);    off += (size_t)512 * EMBD * 4; // 0.6 MB
    ushort_t* whA  = (ushort_t*)(base + off); off += (size_t)9 * WPER * 2;   // 8.1 MB
    ushort_t* vnaB = (ushort_t*)(base + off); off += (size_t)GG * KP1 * 2;   // 2.6 MB
    off = (off + 255) & ~(size_t)255;

    // adaptive chunk for tB: KT2*2 = 1216 B per row; prefer single chunk, else 2 balanced
    size_t avail = (ws_size > off) ? ws_size - off : 0;
    int CH = (int)(avail / (KT2 * 2));
    CH &= ~255;
    if (CH >= N) CH = (N + 255) & ~255;                              // single chunk
    else if (CH >= (N + 1) / 2) CH = (((N + 1) / 2) + 255) & ~255;   // 2 balanced chunks
    if (CH < 2048) CH = 2048;  // last resort
    ushort_t* tB = (ushort_t*)(base + off);

    const int BLK = 256;
    int ne4 = N * 75;

    // ---- one-time init ----
    find_starts<<<cdiv(GG + 1, BLK), BLK, 0, stream>>>(batch, starts, N);
    atom_encode_bf<<<cdiv(ne4, BLK), BLK, 0, stream>>>(x, atom_emb, vn_emb, hbuf, N);
    init_vn4<<<cdiv(GG * 75, BLK), BLK, 0, stream>>>(vn_emb, vnbuf);
    bond_combo<<<cdiv(512 * EMBD, BLK), BLK, 0, stream>>>(bond_emb, ebsum);
    conv_all<<<cdiv(9 * WPER, BLK), BLK, 0, stream>>>(gin_W1, gin_W2, vn_W1, vn_W2, whA);
    (void)hipMemsetAsync(cnt, 0, (size_t)N * 4, stream);
    (void)hipMemsetAsync(vnaB, 0, (size_t)GG * KP1 * 2, stream);
    ecount<<<cdiv(E, BLK), BLK, 0, stream>>>(ei, cnt, E);
    scan_part<<<NB, 256, 0, stream>>>(cnt, bsum, N);
    scan_top<<<1, 1024, 0, stream>>>(bsum, NB);
    scan_final<<<NB, 256, 0, stream>>>(cnt, bsum, estart, cnt /*cursor*/, N, E);
    escatter<<<cdiv(E, BLK), BLK, 0, stream>>>(ei, ea, cnt /*cursor*/, epack, E);

    for (int l = 0; l < NLAY; ++l) {
        int last = (l == NLAY - 1);

        if (!last) {
            // vnaB = pool(h) + vn_l  (h already includes vn_l; read-only)
            pool_only<<<GG / 4, 320, 0, stream>>>(hbuf, vnbuf, starts, vnaB);
            // vn_{l+1} = relu(bn2(mlp(vnaB))) -> vnbuf (fp32)
            const ushort_t* w1 = whA + (size_t)(NLAY + l) * WPER;
            const ushort_t* w2 = w1 + NP1 * KP1;
            int mb = cdiv(GG, BMg), mbp = cdiv(mb, 8) * 8;
            gemm_as<<<(NP1 / BNg) * mbp, 256, 0, stream>>>(
                vnaB, KP1, w1, KP1,
                vn_b1 + (size_t)l * 2 * EMBD, vn_bn1g + (size_t)l * 2 * EMBD,
                vn_bn1b + (size_t)l * 2 * EMBD, vn_bn1m + (size_t)l * 2 * EMBD,
                vn_bn1v + (size_t)l * 2 * EMBD,
                GG, 2 * EMBD, 1, NP1 / BNg, mb,
                nullptr, nullptr,
                nullptr, 0, tB, KT2);
            gemm_as<<<(NP2 / BNg) * mbp, 256, 0, stream>>>(
                tB, KT2, w2, KP2,
                vn_b2 + (size_t)l * EMBD, vn_bn2g + (size_t)l * EMBD,
                vn_bn2b + (size_t)l * EMBD, vn_bn2m + (size_t)l * EMBD,
                vn_bn2v + (size_t)l * EMBD,
                GG, EMBD, 1, NP2 / BNg, mb,
                nullptr, nullptr,
                vnbuf, EMBD, nullptr, 0);
        }

        // aggB = bf16( (1+eps)h + sum relu(h[src]+bond) )  -- h unchanged this layer
        aggregate<<<cdiv(N, NPB), NPB * 80, 0, stream>>>(
            hbuf, ebsum, estart, epack, gin_eps + l, aggB, N);

        // h = bn(mlp(aggB)) (+relu and +vn_{l+1} in GEMM2 writer unless last)
        MlpP Wn = { gin_b1 + (size_t)l * 2 * EMBD,
                    gin_bn1g + (size_t)l * 2 * EMBD, gin_bn1b + (size_t)l * 2 * EMBD,
                    gin_bn1m + (size_t)l * 2 * EMBD, gin_bn1v + (size_t)l * 2 * EMBD,
                    gin_b2 + (size_t)l * EMBD,
                    bn_g + (size_t)l * EMBD, bn_b + (size_t)l * EMBD,
                    bn_m + (size_t)l * EMBD, bn_v + (size_t)l * EMBD };
        run_mlp(stream, aggB, N, whA, l, tB, CH, Wn, hbuf, last ? 0 : 1,
                last ? nullptr : vnbuf, batch);
    }

    pool_mean<<<GG / 4, 320, 0, stream>>>(hbuf, starts, (float*)d_out);
}